// Round 8
// baseline (202.082 us; speedup 1.0000x reference)
//
#include <hip/hip_runtime.h>
#include <hip/hip_bf16.h>

typedef __hip_bfloat16 bf16;
typedef __attribute__((ext_vector_type(4))) float f32x4;
typedef __attribute__((ext_vector_type(16))) float f32x16;
typedef __attribute__((ext_vector_type(8))) __bf16 bf16x8;
typedef __attribute__((ext_vector_type(8))) unsigned short u16x8;

#define DEVI static __device__ __forceinline__

DEVI void gload_lds16(const void* g, void* l) {
  __builtin_amdgcn_global_load_lds(
      (const __attribute__((address_space(1))) void*)g,
      (__attribute__((address_space(3))) void*)l, 16, 0, 0);
}

DEVI unsigned pkbf(float a, float b) {
  union { __hip_bfloat162 h2; unsigned u; } t;
  t.h2.x = __float2bfloat16(a);
  t.h2.y = __float2bfloat16(b);
  return t.u;
}

DEVI u16x8 cvt8(f32x4 a, f32x4 b) {
  u16x8 r;
#pragma unroll
  for (int i = 0; i < 4; ++i) { bf16 h = __float2bfloat16(a[i]); r[i] = *reinterpret_cast<unsigned short*>(&h); }
#pragma unroll
  for (int i = 0; i < 4; ++i) { bf16 h = __float2bfloat16(b[i]); r[i + 4] = *reinterpret_cast<unsigned short*>(&h); }
  return r;
}

// ---------------- QKV projection GEMM: f32 inputs, reg-staged cvt, 2-phase dbuf ----------
// grid 1536 1-D, XCD-chunked swizzle (R7-proven). BM=64, BN=128, BK=64, 4 waves.
// Staging: plain f32 loads -> cvt8 -> ds_write_b128 (LDS image identical to R7's
// gload_lds version: lane-linear dest, source slot gs = sslot ^ srow8).
__global__ __launch_bounds__(256) void gemm_zone(
    const float* __restrict__ qf, const float* __restrict__ kvf,
    const float* __restrict__ Wq, const float* __restrict__ Wk, const float* __restrict__ Wv,
    const float* __restrict__ bq, const float* __restrict__ bk, const float* __restrict__ bv,
    bf16* __restrict__ qp, bf16* __restrict__ kp, bf16* __restrict__ vT) {
  constexpr int K = 512;
  __shared__ __align__(16) char smem[49152];
  const int tid = threadIdx.x;
  const int wave = tid >> 6, lane = tid & 63;
  const int bid = blockIdx.x;
  const int wgid = (bid & 7) * 192 + (bid >> 3);
  const int bm = wgid / 12;
  const int rz = wgid % 12;
  const int zone = rz >> 2, bn = rz & 3;
  const float* A = zone ? kvf : qf;
  const float* W = (zone == 0) ? Wq : (zone == 1 ? Wk : Wv);
  const float* bias = (zone == 0) ? bq : (zone == 1 ? bk : bv);
  const int wm = (wave >> 1) * 32, wn = (wave & 1) * 64;
  const int srow8 = lane >> 3, sslot = lane & 7;
  const int gs = sslot ^ srow8;

  f32x4 acc[2][4] = {};

  // staged-load pointers (f32, advance +64 per K-step)
  const float* afp[2];
  const float* wfp[4];
#pragma unroll
  for (int i = 0; i < 2; ++i) {
    int row = (wave * 2 + i) * 8 + srow8;
    afp[i] = A + (long)(bm * 64 + row) * K + gs * 8;
  }
#pragma unroll
  for (int i = 0; i < 4; ++i) {
    int row = (wave * 4 + i) * 8 + srow8;
    wfp[i] = W + (long)(bn * 128 + row) * K + gs * 8;
  }

  int aoff[2][2], boff[2][4];
#pragma unroll
  for (int ks = 0; ks < 2; ++ks) {
#pragma unroll
    for (int f = 0; f < 2; ++f) {
      int r = f * 16 + (lane & 15);
      aoff[ks][f] = (wm + r) * 128 + (((ks * 4 + (lane >> 4)) ^ (r & 7)) << 4);
    }
#pragma unroll
    for (int f = 0; f < 4; ++f) {
      int r = f * 16 + (lane & 15);
      boff[ks][f] = (wn + r) * 128 + (((ks * 4 + (lane >> 4)) ^ (r & 7)) << 4);
    }
  }

  f32x4 a0[2], a1[2], w0[4], w1[4];

#define ZLOAD()                                                           \
  {                                                                       \
    _Pragma("unroll") for (int i = 0; i < 2; ++i) {                       \
      a0[i] = *reinterpret_cast<const f32x4*>(afp[i]);                    \
      a1[i] = *reinterpret_cast<const f32x4*>(afp[i] + 4);                \
      afp[i] += 64;                                                       \
    }                                                                     \
    _Pragma("unroll") for (int i = 0; i < 4; ++i) {                       \
      w0[i] = *reinterpret_cast<const f32x4*>(wfp[i]);                    \
      w1[i] = *reinterpret_cast<const f32x4*>(wfp[i] + 4);                \
      wfp[i] += 64;                                                       \
    }                                                                     \
  }

#define ZWRITE(BUF)                                                       \
  {                                                                       \
    _Pragma("unroll") for (int i = 0; i < 2; ++i)                         \
      *reinterpret_cast<u16x8*>(smem + (BUF) * 24576 +                    \
          (wave * 2 + i) * 1024 + lane * 16) = cvt8(a0[i], a1[i]);        \
    _Pragma("unroll") for (int i = 0; i < 4; ++i)                         \
      *reinterpret_cast<u16x8*>(smem + (BUF) * 24576 + 8192 +             \
          (wave * 4 + i) * 1024 + lane * 16) = cvt8(w0[i], w1[i]);        \
  }

#define ZCOMP(BUF)                                                        \
  {                                                                       \
    const char* Asb = smem + (BUF) * 24576;                               \
    const char* Bsb = Asb + 8192;                                         \
    _Pragma("unroll") for (int ks = 0; ks < 2; ++ks) {                    \
      bf16x8 af[2], bfv[4];                                               \
      _Pragma("unroll") for (int f = 0; f < 2; ++f)                       \
        af[f] = *reinterpret_cast<const bf16x8*>(Asb + aoff[ks][f]);      \
      _Pragma("unroll") for (int f = 0; f < 4; ++f)                       \
        bfv[f] = *reinterpret_cast<const bf16x8*>(Bsb + boff[ks][f]);     \
      _Pragma("unroll") for (int mf = 0; mf < 2; ++mf)                    \
        _Pragma("unroll") for (int nf = 0; nf < 4; ++nf)                  \
          acc[mf][nf] = __builtin_amdgcn_mfma_f32_16x16x32_bf16(          \
              af[mf], bfv[nf], acc[mf][nf], 0, 0, 0);                     \
    }                                                                     \
  }

  ZLOAD()
  ZWRITE(0)
  __syncthreads();
#pragma unroll 1
  for (int tt = 0; tt < 8; tt += 2) {
    // t = tt (even, <=6): compute buf0, stage t+1 -> buf1
    ZLOAD()
    ZCOMP(0)
    __syncthreads();
    ZWRITE(1)
    __syncthreads();
    // t = tt+1 (odd): compute buf1, stage t+2 -> buf0 (skip when t+1==7)
    if (tt + 1 < 7) {
      ZLOAD()
      ZCOMP(1)
      __syncthreads();
      ZWRITE(0)
      __syncthreads();
    } else {
      ZCOMP(1)
    }
  }
#undef ZLOAD
#undef ZWRITE
#undef ZCOMP

#pragma unroll
  for (int nf = 0; nf < 4; ++nf) {
    int col = bn * 128 + wn + nf * 16 + (lane & 15);
    float bia = bias[col];
#pragma unroll
    for (int mf = 0; mf < 2; ++mf) {
      int row0 = bm * 64 + wm + mf * 16 + (lane >> 4) * 4;
      if (zone < 2) {
        bf16* Ob = zone ? kp : qp;
#pragma unroll
        for (int j = 0; j < 4; ++j)
          Ob[(long)(row0 + j) * 512 + col] = __float2bfloat16(acc[mf][nf][j] + bia);
      } else {
        int b = row0 >> 11, s0 = row0 & 2047;
        int h = col >> 6, d = col & 63;
        union { ushort4 s; unsigned short u[4]; } pk;
#pragma unroll
        for (int j = 0; j < 4; ++j) {
          bf16 hv = __float2bfloat16(acc[mf][nf][j] + bia);
          pk.u[j] = *reinterpret_cast<unsigned short*>(&hv);
        }
        *reinterpret_cast<ushort4*>(vT + ((long)((b * 8 + h) * 64 + d)) * 2048 + s0) = pk.s;
      }
    }
  }
}

// ---------------- FFN GEMM: A bf16 (o1), W from f32 Wo, reg-staged, XCD swizzle ----------
__global__ __launch_bounds__(256) void gemm_ffn(
    const bf16* __restrict__ A, const float* __restrict__ W,
    const float* __restrict__ bias, float* __restrict__ Of) {
  constexpr int K = 512;
  __shared__ __align__(16) char smem[49152];
  const int tid = threadIdx.x;
  const int wave = tid >> 6, lane = tid & 63;
  const int bid = blockIdx.x;
  const int wgid = (bid & 7) * 64 + (bid >> 3);
  const int bm = wgid >> 2, bn = wgid & 3;
  const int wm = (wave >> 1) * 32, wn = (wave & 1) * 64;
  const int srow8 = lane >> 3, sslot = lane & 7;
  const int gs = sslot ^ srow8;

  f32x4 acc[2][4] = {};

  const bf16* abp[2];
  const float* wfp[4];
#pragma unroll
  for (int i = 0; i < 2; ++i) {
    int row = (wave * 2 + i) * 8 + srow8;
    abp[i] = A + (long)(bm * 64 + row) * K + gs * 8;
  }
#pragma unroll
  for (int i = 0; i < 4; ++i) {
    int row = (wave * 4 + i) * 8 + srow8;
    wfp[i] = W + (long)(bn * 128 + row) * K + gs * 8;
  }

  int aoff[2][2], boff[2][4];
#pragma unroll
  for (int ks = 0; ks < 2; ++ks) {
#pragma unroll
    for (int f = 0; f < 2; ++f) {
      int r = f * 16 + (lane & 15);
      aoff[ks][f] = (wm + r) * 128 + (((ks * 4 + (lane >> 4)) ^ (r & 7)) << 4);
    }
#pragma unroll
    for (int f = 0; f < 4; ++f) {
      int r = f * 16 + (lane & 15);
      boff[ks][f] = (wn + r) * 128 + (((ks * 4 + (lane >> 4)) ^ (r & 7)) << 4);
    }
  }

  u16x8 areg[2];
  f32x4 w0[4], w1[4];

#define FLOAD()                                                           \
  {                                                                       \
    _Pragma("unroll") for (int i = 0; i < 2; ++i) {                       \
      areg[i] = *reinterpret_cast<const u16x8*>(abp[i]);                  \
      abp[i] += 64;                                                       \
    }                                                                     \
    _Pragma("unroll") for (int i = 0; i < 4; ++i) {                       \
      w0[i] = *reinterpret_cast<const f32x4*>(wfp[i]);                    \
      w1[i] = *reinterpret_cast<const f32x4*>(wfp[i] + 4);                \
      wfp[i] += 64;                                                       \
    }                                                                     \
  }

#define FWRITE(BUF)                                                       \
  {                                                                       \
    _Pragma("unroll") for (int i = 0; i < 2; ++i)                         \
      *reinterpret_cast<u16x8*>(smem + (BUF) * 24576 +                    \
          (wave * 2 + i) * 1024 + lane * 16) = areg[i];                   \
    _Pragma("unroll") for (int i = 0; i < 4; ++i)                         \
      *reinterpret_cast<u16x8*>(smem + (BUF) * 24576 + 8192 +             \
          (wave * 4 + i) * 1024 + lane * 16) = cvt8(w0[i], w1[i]);        \
  }

#define FCOMP(BUF)                                                        \
  {                                                                       \
    const char* Asb = smem + (BUF) * 24576;                               \
    const char* Bsb = Asb + 8192;                                         \
    _Pragma("unroll") for (int ks = 0; ks < 2; ++ks) {                    \
      bf16x8 af[2], bfv[4];                                               \
      _Pragma("unroll") for (int f = 0; f < 2; ++f)                       \
        af[f] = *reinterpret_cast<const bf16x8*>(Asb + aoff[ks][f]);      \
      _Pragma("unroll") for (int f = 0; f < 4; ++f)                       \
        bfv[f] = *reinterpret_cast<const bf16x8*>(Bsb + boff[ks][f]);     \
      _Pragma("unroll") for (int mf = 0; mf < 2; ++mf)                    \
        _Pragma("unroll") for (int nf = 0; nf < 4; ++nf)                  \
          acc[mf][nf] = __builtin_amdgcn_mfma_f32_16x16x32_bf16(          \
              af[mf], bfv[nf], acc[mf][nf], 0, 0, 0);                     \
    }                                                                     \
  }

  FLOAD()
  FWRITE(0)
  __syncthreads();
#pragma unroll 1
  for (int tt = 0; tt < 8; tt += 2) {
    FLOAD()
    FCOMP(0)
    __syncthreads();
    FWRITE(1)
    __syncthreads();
    if (tt + 1 < 7) {
      FLOAD()
      FCOMP(1)
      __syncthreads();
      FWRITE(0)
      __syncthreads();
    } else {
      FCOMP(1)
    }
  }
#undef FLOAD
#undef FWRITE
#undef FCOMP

#pragma unroll
  for (int nf = 0; nf < 4; ++nf) {
    int col = bn * 128 + wn + nf * 16 + (lane & 15);
    float bia = bias[col];
#pragma unroll
    for (int mf = 0; mf < 2; ++mf) {
#pragma unroll
      for (int j = 0; j < 4; ++j) {
        int row = bm * 64 + wm + mf * 16 + (lane >> 4) * 4 + j;
        float r = __bfloat162float(A[(long)row * 512 + col]);
        Of[(long)row * 512 + col] = r + fmaxf(acc[mf][nf][j] + bia, 0.f);
      }
    }
  }
}

// ---------------- attention (R7/R4-proven, UNCHANGED) ----------------
__global__ __launch_bounds__(256) void attn_k(
    const bf16* __restrict__ Q, const bf16* __restrict__ Kp,
    const bf16* __restrict__ VT, bf16* __restrict__ O) {
  __shared__ __align__(16) char smem[32768];
  const int tid = threadIdx.x, wave = tid >> 6, lane = tid & 63;
  const int bh = blockIdx.y, b = bh >> 3, h = bh & 7;
  const int q0 = blockIdx.x * 128 + wave * 32;
  const int ql = lane & 31, hl = lane >> 5;
  const long qg = ((long)(b * 2048 + q0 + ql)) * 512 + h * 64;
  const int srow8 = lane >> 3, sslot = lane & 7;

  bf16x8 qf[4];
#pragma unroll
  for (int c = 0; c < 4; ++c)
    qf[c] = *reinterpret_cast<const bf16x8*>(Q + qg + c * 16 + hl * 8);

  bf16x8 ones;
#pragma unroll
  for (int j = 0; j < 8; ++j) ones[j] = (__bf16)1.0f;

  f32x16 oacc[2] = {};
  f32x16 lacc = {};
  float m = -INFINITY;
  const float CEXP = 0.125f * 1.44269504088896f;

  const bf16* kgp[2];
  const bf16* vgp[2];
  char* kdst[2];
  char* vdst[2];
#pragma unroll
  for (int i = 0; i < 2; ++i) {
    int c = wave * 2 + i;
    int row = c * 8 + srow8;
    int gs = sslot ^ (row & 7);
    kgp[i] = Kp + ((long)(b * 2048 + row)) * 512 + h * 64 + gs * 8;
    vgp[i] = VT + ((long)(bh * 64 + row)) * 2048 + gs * 8;
    kdst[i] = smem + c * 1024;
    vdst[i] = smem + 8192 + c * 1024;
  }

  int ofs[2][4];
#pragma unroll
  for (int s = 0; s < 2; ++s)
#pragma unroll
    for (int c = 0; c < 4; ++c) {
      int row = s * 32 + ql;
      ofs[s][c] = row * 128 + (((c * 2 + hl) ^ (row & 7)) << 4);
    }

#define ASTAGE(BUF)                                                       \
  _Pragma("unroll") for (int i = 0; i < 2; ++i) {                         \
    gload_lds16(kgp[i], kdst[i] + (BUF) * 16384);                         \
    gload_lds16(vgp[i], vdst[i] + (BUF) * 16384);                         \
    kgp[i] += 32768; vgp[i] += 64;                                        \
  }

#define ABODY(BUF, LAST)                                                  \
  {                                                                       \
    if (!(LAST)) {                                                        \
      ASTAGE((BUF) ^ 1)                                                   \
      asm volatile("s_waitcnt vmcnt(4)" ::: "memory");                    \
    } else {                                                              \
      asm volatile("s_waitcnt vmcnt(0)" ::: "memory");                    \
    }                                                                     \
    asm volatile("s_barrier" ::: "memory");                               \
    const char* Kb = smem + (BUF) * 16384;                                \
    const char* Vb = Kb + 8192;                                           \
    f32x16 sacc[2] = {};                                                  \
    __builtin_amdgcn_s_setprio(1);                                        \
    _Pragma("unroll") for (int s = 0; s < 2; ++s)                         \
      _Pragma("unroll") for (int c = 0; c < 4; ++c) {                     \
        bf16x8 kf = *reinterpret_cast<const bf16x8*>(Kb + ofs[s][c]);     \
        sacc[s] = __builtin_amdgcn_mfma_f32_32x32x16_bf16(                \
            kf, qf[c], sacc[s], 0, 0, 0);                                 \
      }                                                                   \
    __builtin_amdgcn_s_setprio(0);                                        \
    float pmax = fmaxf(sacc[0][0], sacc[0][1]);                           \
    _Pragma("unroll") for (int i = 2; i < 16; i += 2)                     \
      pmax = fmaxf(fmaxf(pmax, sacc[0][i]), sacc[0][i + 1]);              \
    _Pragma("unroll") for (int i = 0; i < 16; i += 2)                     \
      pmax = fmaxf(fmaxf(pmax, sacc[1][i]), sacc[1][i + 1]);              \
    pmax = fmaxf(pmax, __shfl_xor(pmax, 32));                             \
    if (!__all(pmax - m <= 44.3614195558365f)) {                          \
      float mn = fmaxf(m, pmax);                                          \
      float al = exp2f((m - mn) * CEXP);                                  \
      m = mn;                                                             \
      _Pragma("unroll") for (int i = 0; i < 16; ++i) {                    \
        oacc[0][i] *= al; oacc[1][i] *= al; lacc[i] *= al;                \
      }                                                                   \
    }                                                                     \
    float nmC = -m * CEXP;                                                \
    float p[32];                                                          \
    _Pragma("unroll") for (int s = 0; s < 2; ++s)                         \
      _Pragma("unroll") for (int i = 0; i < 16; ++i)                      \
        p[s * 16 + i] = exp2f(fmaf(sacc[s][i], CEXP, nmC));               \
    __builtin_amdgcn_s_setprio(1);                                        \
    _Pragma("unroll") for (int s = 0; s < 2; ++s)                         \
      _Pragma("unroll") for (int jj = 0; jj < 2; ++jj) {                  \
        int base = s * 16 + jj * 8;                                       \
        unsigned w0 = pkbf(p[base + 0], p[base + 1]);                     \
        unsigned w1 = pkbf(p[base + 2], p[base + 3]);                     \
        unsigned w2 = pkbf(p[base + 4], p[base + 5]);                     \
        unsigned w3 = pkbf(p[base + 6], p[base + 7]);                     \
        asm("v_permlane32_swap_b32 %0, %1" : "+v"(w0), "+v"(w2));         \
        asm("v_permlane32_swap_b32 %0, %1" : "+v"(w1), "+v"(w3));         \
        union { unsigned u[4]; bf16x8 v; } pf;                            \
        pf.u[0] = w0; pf.u[1] = w1; pf.u[2] = w2; pf.u[3] = w3;           \
        lacc = __builtin_amdgcn_mfma_f32_32x32x16_bf16(                   \
            ones, pf.v, lacc, 0, 0, 0);                                   \
        int j = s * 2 + jj;                                               \
        _Pragma("unroll") for (int dblk = 0; dblk < 2; ++dblk) {          \
          bf16x8 vf = *reinterpret_cast<const bf16x8*>(Vb + ofs[dblk][j]);\
          oacc[dblk] = __builtin_amdgcn_mfma_f32_32x32x16_bf16(           \
              vf, pf.v, oacc[dblk], 0, 0, 0);                             \
        }                                                                 \
      }                                                                   \
    __builtin_amdgcn_s_setprio(0);                                        \
    asm volatile("s_barrier" ::: "memory");                               \
  }

  ASTAGE(0)
#pragma unroll 1
  for (int tt = 0; tt < 16; ++tt) {
    ABODY(0, false)
    ABODY(1, tt == 15)
  }
#undef ASTAGE
#undef ABODY

  float rl = 1.0f / lacc[0];
#pragma unroll
  for (int dblk = 0; dblk < 2; ++dblk) {
#pragma unroll
    for (int g = 0; g < 4; ++g) {
      int d0 = dblk * 32 + g * 8 + hl * 4;
      const long ga = qg + d0;
      union { ushort4 s; unsigned short u[4]; } qin, ov;
      qin.s = *reinterpret_cast<const ushort4*>(Q + ga);
#pragma unroll
      for (int i = 0; i < 4; ++i) {
        float qvf = __uint_as_float((unsigned)qin.u[i] << 16);
        float r = qvf + oacc[dblk][g * 4 + i] * rl;
        bf16 hb = __float2bfloat16(r);
        ov.u[i] = *reinterpret_cast<unsigned short*>(&hb);
      }
      *reinterpret_cast<ushort4*>(O + ga) = ov.s;
    }
  }
}

// ---------------- launch (3 dispatches) ----------------
extern "C" void kernel_launch(void* const* d_in, const int* in_sizes, int n_in,
                              void* d_out, int out_size, void* d_ws, size_t ws_size,
                              hipStream_t stream) {
  const float* query = (const float*)d_in[0];
  const float* keyv  = (const float*)d_in[1];
  const float* Wq = (const float*)d_in[2];
  const float* bq = (const float*)d_in[3];
  const float* Wk = (const float*)d_in[4];
  const float* bk = (const float*)d_in[5];
  const float* Wv = (const float*)d_in[6];
  const float* bv = (const float*)d_in[7];
  const float* Wo = (const float*)d_in[8];
  const float* bo = (const float*)d_in[9];
  float* out = (float*)d_out;
  char* ws = (char*)d_ws;

  bf16* qp = (bf16*)(ws + 18874368);
  bf16* kp = (bf16*)(ws + 27262976);
  bf16* vT = (bf16*)(ws + 35651584);
  bf16* o1 = (bf16*)(ws + 44040192);

  gemm_zone<<<1536, 256, 0, stream>>>(query, keyv, Wq, Wk, Wv, bq, bk, bv, qp, kp, vT);

  attn_k<<<dim3(16, 32), 256, 0, stream>>>(qp, kp, vT, o1);

  gemm_ffn<<<512, 256, 0, stream>>>(o1, Wo, bo, out);
}

// Round 10
// 190.555 us; speedup vs baseline: 1.0605x; 1.0605x over previous
//
#include <hip/hip_runtime.h>
#include <hip/hip_bf16.h>

typedef __hip_bfloat16 bf16;
typedef __attribute__((ext_vector_type(4))) float f32x4;
typedef __attribute__((ext_vector_type(16))) float f32x16;
typedef __attribute__((ext_vector_type(8))) __bf16 bf16x8;

#define DEVI static __device__ __forceinline__

DEVI void gload_lds16(const void* g, void* l) {
  __builtin_amdgcn_global_load_lds(
      (const __attribute__((address_space(1))) void*)g,
      (__attribute__((address_space(3))) void*)l, 16, 0, 0);
}

// pack two f32 -> u32 of 2 bf16 via single HW instruction (T12; RNE like __float2bfloat16)
DEVI unsigned pkbf(float a, float b) {
  unsigned r;
  asm("v_cvt_pk_bf16_f32 %0, %1, %2" : "=v"(r) : "v"(a), "v"(b));
  return r;
}

// ---------------- merged f32 -> bf16 converter ----------------
union PK4 { bf16 h[4]; unsigned long long ll; };

DEVI unsigned long long pack4(float4 v) {
  PK4 u;
  u.h[0] = __float2bfloat16(v.x); u.h[1] = __float2bfloat16(v.y);
  u.h[2] = __float2bfloat16(v.z); u.h[3] = __float2bfloat16(v.w);
  return u.ll;
}

__global__ void cvt_all(const float* __restrict__ q, const float* __restrict__ kv,
                        const float* __restrict__ wq, const float* __restrict__ wk,
                        const float* __restrict__ wv, const float* __restrict__ wo,
                        bf16* __restrict__ oq, bf16* __restrict__ okv,
                        bf16* __restrict__ owq, bf16* __restrict__ owk,
                        bf16* __restrict__ owv, bf16* __restrict__ owo) {
  int bid = blockIdx.x;
  if (bid < 4096) {
    int i = bid * 256 + threadIdx.x;
    reinterpret_cast<unsigned long long*>(oq)[i]  = pack4(reinterpret_cast<const float4*>(q)[i]);
    reinterpret_cast<unsigned long long*>(okv)[i] = pack4(reinterpret_cast<const float4*>(kv)[i]);
  } else {
    int i = (bid - 4096) * 256 + threadIdx.x;
    reinterpret_cast<unsigned long long*>(owq)[i] = pack4(reinterpret_cast<const float4*>(wq)[i]);
    reinterpret_cast<unsigned long long*>(owk)[i] = pack4(reinterpret_cast<const float4*>(wk)[i]);
    reinterpret_cast<unsigned long long*>(owv)[i] = pack4(reinterpret_cast<const float4*>(wv)[i]);
    reinterpret_cast<unsigned long long*>(owo)[i] = pack4(reinterpret_cast<const float4*>(wo)[i]);
  }
}

// ---------------- QKV projection GEMM: BM=64, BN=128, BK=64, 4 waves, 2-phase ----------------
// grid 1536 1-D, XCD-chunked swizzle. LDS 2 x 24KB = 48KB -> 3 blocks/CU.
__global__ __launch_bounds__(256) void gemm_zone(
    const bf16* __restrict__ qb, const bf16* __restrict__ kvb,
    const bf16* __restrict__ wqb, const bf16* __restrict__ wkb, const bf16* __restrict__ wvb,
    const float* __restrict__ bq, const float* __restrict__ bk, const float* __restrict__ bv,
    bf16* __restrict__ qp, bf16* __restrict__ kp, bf16* __restrict__ vT) {
  constexpr int K = 512;
  __shared__ __align__(16) char smem[49152];
  const int tid = threadIdx.x;
  const int wave = tid >> 6, lane = tid & 63;
  const int bid = blockIdx.x;
  const int wgid = (bid & 7) * 192 + (bid >> 3);
  const int bm = wgid / 12;
  const int rz = wgid % 12;
  const int zone = rz >> 2, bn = rz & 3;
  const bf16* A = zone ? kvb : qb;
  const bf16* W = (zone == 0) ? wqb : (zone == 1 ? wkb : wvb);
  const float* bias = (zone == 0) ? bq : (zone == 1 ? bk : bv);
  const int wm = (wave >> 1) * 32, wn = (wave & 1) * 64;
  const int srow8 = lane >> 3, sslot = lane & 7;

  f32x4 acc[2][4] = {};

  const bf16* ap[2];
  const bf16* wp[4];
  char* adst[2];
  char* bdst[4];
#pragma unroll
  for (int i = 0; i < 2; ++i) {
    int c = wave * 2 + i;
    int row = c * 8 + srow8;
    int gs = sslot ^ (row & 7);
    ap[i] = A + (long)(bm * 64 + row) * K + gs * 8;
    adst[i] = smem + c * 1024;
  }
#pragma unroll
  for (int i = 0; i < 4; ++i) {
    int c = wave * 4 + i;
    int row = c * 8 + srow8;
    int gs = sslot ^ (row & 7);
    wp[i] = W + (long)(bn * 128 + row) * K + gs * 8;
    bdst[i] = smem + 8192 + c * 1024;
  }

  int aoff[2][2], boff[2][4];
#pragma unroll
  for (int ks = 0; ks < 2; ++ks) {
#pragma unroll
    for (int f = 0; f < 2; ++f) {
      int r = f * 16 + (lane & 15);
      aoff[ks][f] = (wm + r) * 128 + (((ks * 4 + (lane >> 4)) ^ (r & 7)) << 4);
    }
#pragma unroll
    for (int f = 0; f < 4; ++f) {
      int r = f * 16 + (lane & 15);
      boff[ks][f] = (wn + r) * 128 + (((ks * 4 + (lane >> 4)) ^ (r & 7)) << 4);
    }
  }

#define ZSTAGE(BUF)                                                       \
  {                                                                       \
    _Pragma("unroll") for (int i = 0; i < 2; ++i) {                       \
      gload_lds16(ap[i], adst[i] + (BUF) * 24576);                        \
      ap[i] += 64;                                                        \
    }                                                                     \
    _Pragma("unroll") for (int i = 0; i < 4; ++i) {                       \
      gload_lds16(wp[i], bdst[i] + (BUF) * 24576);                        \
      wp[i] += 64;                                                        \
    }                                                                     \
  }

#define ZBODY(BUF, LAST)                                                  \
  {                                                                       \
    if (!(LAST)) {                                                        \
      ZSTAGE((BUF) ^ 1)                                                   \
      asm volatile("s_waitcnt vmcnt(6)" ::: "memory");                    \
    } else {                                                              \
      asm volatile("s_waitcnt vmcnt(0)" ::: "memory");                    \
    }                                                                     \
    asm volatile("s_barrier" ::: "memory");                               \
    const char* Asb = smem + (BUF) * 24576;                               \
    const char* Bsb = Asb + 8192;                                         \
    _Pragma("unroll") for (int ks = 0; ks < 2; ++ks) {                    \
      bf16x8 af[2], bfv[4];                                               \
      _Pragma("unroll") for (int f = 0; f < 2; ++f)                       \
        af[f] = *reinterpret_cast<const bf16x8*>(Asb + aoff[ks][f]);      \
      _Pragma("unroll") for (int f = 0; f < 4; ++f)                       \
        bfv[f] = *reinterpret_cast<const bf16x8*>(Bsb + boff[ks][f]);     \
      _Pragma("unroll") for (int mf = 0; mf < 2; ++mf)                    \
        _Pragma("unroll") for (int nf = 0; nf < 4; ++nf)                  \
          acc[mf][nf] = __builtin_amdgcn_mfma_f32_16x16x32_bf16(          \
              af[mf], bfv[nf], acc[mf][nf], 0, 0, 0);                     \
    }                                                                     \
    asm volatile("s_barrier" ::: "memory");                               \
  }

  ZSTAGE(0)
#pragma unroll 1
  for (int kt = 0; kt < 8; kt += 2) {
    ZBODY(0, false)
    ZBODY(1, kt + 1 == 7)
  }
#undef ZSTAGE
#undef ZBODY

#pragma unroll
  for (int nf = 0; nf < 4; ++nf) {
    int col = bn * 128 + wn + nf * 16 + (lane & 15);
    float bia = bias[col];
#pragma unroll
    for (int mf = 0; mf < 2; ++mf) {
      int row0 = bm * 64 + wm + mf * 16 + (lane >> 4) * 4;
      if (zone < 2) {
        bf16* Ob = zone ? kp : qp;
#pragma unroll
        for (int j = 0; j < 4; ++j)
          Ob[(long)(row0 + j) * 512 + col] = __float2bfloat16(acc[mf][nf][j] + bia);
      } else {
        int b = row0 >> 11, s0 = row0 & 2047;
        int h = col >> 6, d = col & 63;
        union { ushort4 s; unsigned short u[4]; } pk;
#pragma unroll
        for (int j = 0; j < 4; ++j) {
          bf16 hv = __float2bfloat16(acc[mf][nf][j] + bia);
          pk.u[j] = *reinterpret_cast<unsigned short*>(&hv);
        }
        *reinterpret_cast<ushort4*>(vT + ((long)((b * 8 + h) * 64 + d)) * 2048 + s0) = pk.s;
      }
    }
  }
}

// ---------------- FFN GEMM: out = resid + relu(resid @ Wo^T + bo), 2-phase + XCD swizzle ----
__global__ __launch_bounds__(256) void gemm_ffn(
    const bf16* __restrict__ A, const bf16* __restrict__ W,
    const float* __restrict__ bias, float* __restrict__ Of) {
  constexpr int K = 512;
  __shared__ __align__(16) char smem[49152];
  const int tid = threadIdx.x;
  const int wave = tid >> 6, lane = tid & 63;
  const int bid = blockIdx.x;
  const int wgid = (bid & 7) * 64 + (bid >> 3);
  const int bm = wgid >> 2, bn = wgid & 3;
  const int wm = (wave >> 1) * 32, wn = (wave & 1) * 64;
  const int srow8 = lane >> 3, sslot = lane & 7;

  f32x4 acc[2][4] = {};

  const bf16* ap[2];
  const bf16* wp[4];
  char* adst[2];
  char* bdst[4];
#pragma unroll
  for (int i = 0; i < 2; ++i) {
    int c = wave * 2 + i;
    int row = c * 8 + srow8;
    int gs = sslot ^ (row & 7);
    ap[i] = A + (long)(bm * 64 + row) * K + gs * 8;
    adst[i] = smem + c * 1024;
  }
#pragma unroll
  for (int i = 0; i < 4; ++i) {
    int c = wave * 4 + i;
    int row = c * 8 + srow8;
    int gs = sslot ^ (row & 7);
    wp[i] = W + (long)(bn * 128 + row) * K + gs * 8;
    bdst[i] = smem + 8192 + c * 1024;
  }

  int aoff[2][2], boff[2][4];
#pragma unroll
  for (int ks = 0; ks < 2; ++ks) {
#pragma unroll
    for (int f = 0; f < 2; ++f) {
      int r = f * 16 + (lane & 15);
      aoff[ks][f] = (wm + r) * 128 + (((ks * 4 + (lane >> 4)) ^ (r & 7)) << 4);
    }
#pragma unroll
    for (int f = 0; f < 4; ++f) {
      int r = f * 16 + (lane & 15);
      boff[ks][f] = (wn + r) * 128 + (((ks * 4 + (lane >> 4)) ^ (r & 7)) << 4);
    }
  }

#define FSTAGE(BUF)                                                       \
  {                                                                       \
    _Pragma("unroll") for (int i = 0; i < 2; ++i) {                       \
      gload_lds16(ap[i], adst[i] + (BUF) * 24576);                        \
      ap[i] += 64;                                                        \
    }                                                                     \
    _Pragma("unroll") for (int i = 0; i < 4; ++i) {                       \
      gload_lds16(wp[i], bdst[i] + (BUF) * 24576);                        \
      wp[i] += 64;                                                        \
    }                                                                     \
  }

#define FBODY(BUF, LAST)                                                  \
  {                                                                       \
    if (!(LAST)) {                                                        \
      FSTAGE((BUF) ^ 1)                                                   \
      asm volatile("s_waitcnt vmcnt(6)" ::: "memory");                    \
    } else {                                                              \
      asm volatile("s_waitcnt vmcnt(0)" ::: "memory");                    \
    }                                                                     \
    asm volatile("s_barrier" ::: "memory");                               \
    const char* Asb = smem + (BUF) * 24576;                               \
    const char* Bsb = Asb + 8192;                                         \
    _Pragma("unroll") for (int ks = 0; ks < 2; ++ks) {                    \
      bf16x8 af[2], bfv[4];                                               \
      _Pragma("unroll") for (int f = 0; f < 2; ++f)                       \
        af[f] = *reinterpret_cast<const bf16x8*>(Asb + aoff[ks][f]);      \
      _Pragma("unroll") for (int f = 0; f < 4; ++f)                       \
        bfv[f] = *reinterpret_cast<const bf16x8*>(Bsb + boff[ks][f]);     \
      _Pragma("unroll") for (int mf = 0; mf < 2; ++mf)                    \
        _Pragma("unroll") for (int nf = 0; nf < 4; ++nf)                  \
          acc[mf][nf] = __builtin_amdgcn_mfma_f32_16x16x32_bf16(          \
              af[mf], bfv[nf], acc[mf][nf], 0, 0, 0);                     \
    }                                                                     \
    asm volatile("s_barrier" ::: "memory");                               \
  }

  FSTAGE(0)
#pragma unroll 1
  for (int kt = 0; kt < 8; kt += 2) {
    FBODY(0, false)
    FBODY(1, kt + 1 == 7)
  }
#undef FSTAGE
#undef FBODY

#pragma unroll
  for (int nf = 0; nf < 4; ++nf) {
    int col = bn * 128 + wn + nf * 16 + (lane & 15);
    float bia = bias[col];
#pragma unroll
    for (int mf = 0; mf < 2; ++mf) {
#pragma unroll
      for (int j = 0; j < 4; ++j) {
        int row = bm * 64 + wm + mf * 16 + (lane >> 4) * 4 + j;
        float r = __bfloat162float(A[(long)row * 512 + col]);
        Of[(long)row * 512 + col] = r + fmaxf(acc[mf][nf][j] + bia, 0.f);
      }
    }
  }
}

// ---------------- attention (R4/R7 structure; pkbf -> v_cvt_pk_bf16_f32) ----------------
__global__ __launch_bounds__(256) void attn_k(
    const bf16* __restrict__ Q, const bf16* __restrict__ Kp,
    const bf16* __restrict__ VT, bf16* __restrict__ O) {
  __shared__ __align__(16) char smem[32768];
  const int tid = threadIdx.x, wave = tid >> 6, lane = tid & 63;
  const int bh = blockIdx.y, b = bh >> 3, h = bh & 7;
  const int q0 = blockIdx.x * 128 + wave * 32;
  const int ql = lane & 31, hl = lane >> 5;
  const long qg = ((long)(b * 2048 + q0 + ql)) * 512 + h * 64;
  const int srow8 = lane >> 3, sslot = lane & 7;

  bf16x8 qf[4];
#pragma unroll
  for (int c = 0; c < 4; ++c)
    qf[c] = *reinterpret_cast<const bf16x8*>(Q + qg + c * 16 + hl * 8);

  bf16x8 ones;
#pragma unroll
  for (int j = 0; j < 8; ++j) ones[j] = (__bf16)1.0f;

  f32x16 oacc[2] = {};
  f32x16 lacc = {};
  float m = -INFINITY;
  const float CEXP = 0.125f * 1.44269504088896f;

  const bf16* kgp[2];
  const bf16* vgp[2];
  char* kdst[2];
  char* vdst[2];
#pragma unroll
  for (int i = 0; i < 2; ++i) {
    int c = wave * 2 + i;
    int row = c * 8 + srow8;
    int gs = sslot ^ (row & 7);
    kgp[i] = Kp + ((long)(b * 2048 + row)) * 512 + h * 64 + gs * 8;
    vgp[i] = VT + ((long)(bh * 64 + row)) * 2048 + gs * 8;
    kdst[i] = smem + c * 1024;
    vdst[i] = smem + 8192 + c * 1024;
  }

  int ofs[2][4];
#pragma unroll
  for (int s = 0; s < 2; ++s)
#pragma unroll
    for (int c = 0; c < 4; ++c) {
      int row = s * 32 + ql;
      ofs[s][c] = row * 128 + (((c * 2 + hl) ^ (row & 7)) << 4);
    }

#define ASTAGE(BUF)                                                       \
  _Pragma("unroll") for (int i = 0; i < 2; ++i) {                         \
    gload_lds16(kgp[i], kdst[i] + (BUF) * 16384);                         \
    gload_lds16(vgp[i], vdst[i] + (BUF) * 16384);                         \
    kgp[i] += 32768; vgp[i] += 64;                                        \
  }

#define ABODY(BUF, LAST)                                                  \
  {                                                                       \
    if (!(LAST)) {                                                        \
      ASTAGE((BUF) ^ 1)                                                   \
      asm volatile("s_waitcnt vmcnt(4)" ::: "memory");                    \
    } else {                                                              \
      asm volatile("s_waitcnt vmcnt(0)" ::: "memory");                    \
    }                                                                     \
    asm volatile("s_barrier" ::: "memory");                               \
    const char* Kb = smem + (BUF) * 16384;                                \
    const char* Vb = Kb + 8192;                                           \
    f32x16 sacc[2] = {};                                                  \
    __builtin_amdgcn_s_setprio(1);                                        \
    _Pragma("unroll") for (int s = 0; s < 2; ++s)                         \
      _Pragma("unroll") for (int c = 0; c < 4; ++c) {                     \
        bf16x8 kf = *reinterpret_cast<const bf16x8*>(Kb + ofs[s][c]);     \
        sacc[s] = __builtin_amdgcn_mfma_f32_32x32x16_bf16(                \
            kf, qf[c], sacc[s], 0, 0, 0);                                 \
      }                                                                   \
    __builtin_amdgcn_s_setprio(0);                                        \
    float pmax = fmaxf(sacc[0][0], sacc[0][1]);                           \
    _Pragma("unroll") for (int i = 2; i < 16; i += 2)                     \
      pmax = fmaxf(fmaxf(pmax, sacc[0][i]), sacc[0][i + 1]);              \
    _Pragma("unroll") for (int i = 0; i < 16; i += 2)                     \
      pmax = fmaxf(fmaxf(pmax, sacc[1][i]), sacc[1][i + 1]);              \
    pmax = fmaxf(pmax, __shfl_xor(pmax, 32));                             \
    if (!__all(pmax - m <= 44.3614195558365f)) {                          \
      float mn = fmaxf(m, pmax);                                          \
      float al = exp2f((m - mn) * CEXP);                                  \
      m = mn;                                                             \
      _Pragma("unroll") for (int i = 0; i < 16; ++i) {                    \
        oacc[0][i] *= al; oacc[1][i] *= al; lacc[i] *= al;                \
      }                                                                   \
    }                                                                     \
    float nmC = -m * CEXP;                                                \
    float p[32];                                                          \
    _Pragma("unroll") for (int s = 0; s < 2; ++s)                         \
      _Pragma("unroll") for (int i = 0; i < 16; ++i)                      \
        p[s * 16 + i] = exp2f(fmaf(sacc[s][i], CEXP, nmC));               \
    __builtin_amdgcn_s_setprio(1);                                        \
    _Pragma("unroll") for (int s = 0; s < 2; ++s)                         \
      _Pragma("unroll") for (int jj = 0; jj < 2; ++jj) {                  \
        int base = s * 16 + jj * 8;                                       \
        unsigned w0 = pkbf(p[base + 0], p[base + 1]);                     \
        unsigned w1 = pkbf(p[base + 2], p[base + 3]);                     \
        unsigned w2 = pkbf(p[base + 4], p[base + 5]);                     \
        unsigned w3 = pkbf(p[base + 6], p[base + 7]);                     \
        asm("v_permlane32_swap_b32 %0, %1" : "+v"(w0), "+v"(w2));         \
        asm("v_permlane32_swap_b32 %0, %1" : "+v"(w1), "+v"(w3));         \
        union { unsigned u[4]; bf16x8 v; } pf;                            \
        pf.u[0] = w0; pf.u[1] = w1; pf.u[2] = w2; pf.u[3] = w3;           \
        lacc = __builtin_amdgcn_mfma_f32_32x32x16_bf16(                   \
            ones, pf.v, lacc, 0, 0, 0);                                   \
        int j = s * 2 + jj;                                               \
        _Pragma("unroll") for (int dblk = 0; dblk < 2; ++dblk) {          \
          bf16x8 vf = *reinterpret_cast<const bf16x8*>(Vb + ofs[dblk][j]);\
          oacc[dblk] = __builtin_amdgcn_mfma_f32_32x32x16_bf16(           \
              vf, pf.v, oacc[dblk], 0, 0, 0);                             \
        }                                                                 \
      }                                                                   \
    __builtin_amdgcn_s_setprio(0);                                        \
    asm volatile("s_barrier" ::: "memory");                               \
  }

  ASTAGE(0)
#pragma unroll 1
  for (int tt = 0; tt < 16; ++tt) {
    ABODY(0, false)
    ABODY(1, tt == 15)
  }
#undef ASTAGE
#undef ABODY

  float rl = 1.0f / lacc[0];
#pragma unroll
  for (int dblk = 0; dblk < 2; ++dblk) {
#pragma unroll
    for (int g = 0; g < 4; ++g) {
      int d0 = dblk * 32 + g * 8 + hl * 4;
      const long ga = qg + d0;
      union { ushort4 s; unsigned short u[4]; } qin, ov;
      qin.s = *reinterpret_cast<const ushort4*>(Q + ga);
#pragma unroll
      for (int i = 0; i < 4; ++i) {
        float qvf = __uint_as_float((unsigned)qin.u[i] << 16);
        float r = qvf + oacc[dblk][g * 4 + i] * rl;
        bf16 hb = __float2bfloat16(r);
        ov.u[i] = *reinterpret_cast<unsigned short*>(&hb);
      }
      *reinterpret_cast<ushort4*>(O + ga) = ov.s;
    }
  }
}

// ---------------- launch ----------------
extern "C" void kernel_launch(void* const* d_in, const int* in_sizes, int n_in,
                              void* d_out, int out_size, void* d_ws, size_t ws_size,
                              hipStream_t stream) {
  const float* query = (const float*)d_in[0];
  const float* keyv  = (const float*)d_in[1];
  const float* Wq = (const float*)d_in[2];
  const float* bq = (const float*)d_in[3];
  const float* Wk = (const float*)d_in[4];
  const float* bk = (const float*)d_in[5];
  const float* Wv = (const float*)d_in[6];
  const float* bv = (const float*)d_in[7];
  const float* Wo = (const float*)d_in[8];
  const float* bo = (const float*)d_in[9];
  float* out = (float*)d_out;
  char* ws = (char*)d_ws;

  bf16* qb  = (bf16*)(ws + 0);
  bf16* kvb = (bf16*)(ws + 8388608);
  bf16* wqb = (bf16*)(ws + 16777216);
  bf16* wkb = (bf16*)(ws + 17301504);
  bf16* wvb = (bf16*)(ws + 17825792);
  bf16* wob = (bf16*)(ws + 18350080);
  bf16* qp  = (bf16*)(ws + 18874368);
  bf16* kp  = (bf16*)(ws + 27262976);
  bf16* vT  = (bf16*)(ws + 35651584);
  bf16* o1  = (bf16*)(ws + 44040192);

  cvt_all<<<4352, 256, 0, stream>>>(query, keyv, Wq, Wk, Wv, Wo,
                                    qb, kvb, wqb, wkb, wvb, wob);

  gemm_zone<<<1536, 256, 0, stream>>>(qb, kvb, wqb, wkb, wvb, bq, bk, bv, qp, kp, vT);

  attn_k<<<dim3(16, 32), 256, 0, stream>>>(qp, kp, vT, o1);

  gemm_ffn<<<512, 256, 0, stream>>>(o1, wob, bo, out);
}